// Round 1
// baseline (358.083 us; speedup 1.0000x reference)
//
#include <hip/hip_runtime.h>

// ImageWiseConv2d: per-sample conv, images [64,64,128,128] f32, kernels [64,64,3,3] f32
// out [64,1,126,126] f32 (VALID, stride 1).
//
// Memory-bound (4.3 FLOP/B). Structure: 512 blocks (64 samples x 8 row-tiles of 16
// output rows x full 126-wide), 256 threads, double-buffered LDS channel loop.
// Zero column halo; all global loads are 16B coalesced; weights go through scalar cache.

#define NS   64
#define CCH  64
#define HH   128
#define WW   128
#define OHH  126
#define OWW  126
#define TH   16      // output rows per tile
#define IR   18      // input rows per tile
#define LDW  132     // LDS row stride (floats): 4-bank shift per row, 16B-aligned
#define LDW4 33      // LDS row stride in float4

__global__ __launch_bounds__(256, 2)
void ImageWiseConv2d_kernel(const float* __restrict__ img,
                            const float* __restrict__ ker,
                            float* __restrict__ out)
{
    __shared__ float buf[2][IR * LDW];

    const int tid = threadIdx.x;
    const int bx  = blockIdx.x;       // 0..511
    const int n   = bx >> 3;
    const int bt  = bx & 7;
    const int h0  = bt * TH;

    // ---- loader mapping (float4 granularity; 18 rows x 32 float4) ----
    const int tx32 = tid & 31;        // float4 column 0..31
    const int rb   = tid >> 5;        // base row 0..7; chunk k adds 8 rows
    const float4* img4 = (const float4*)img;
    // float4 index of (n, c=0, row h0+rb, col 4*tx32)
    int gbase = (n * CCH) * (HH * WW / 4) + (h0 + rb) * (WW / 4) + tx32;
    const bool w2 = (rb < 2);                       // row rb+16 < 18 (in-tile)
    const bool g2 = w2 && (h0 + rb + 16 < HH);      // and in-image
    const int lw0 = rb * LDW4 + tx32;               // LDS float4 write offset, k adds 8*LDW4

    // ---- compute mapping: thread = 2 rows x 4 cols of output ----
    const int tx = tid & 31;          // output col group: cols 4*tx..4*tx+3
    const int ty = tid >> 5;          // 0..7 -> rows 2*ty, 2*ty+1
    const int r0 = 2 * ty;
    const int c0 = 4 * tx;

    float acc0[4] = {0.f, 0.f, 0.f, 0.f};
    float acc1[4] = {0.f, 0.f, 0.f, 0.f};

    // ---- stage channel 0 ----
    {
        float4 p0 = img4[gbase];
        float4 p1 = img4[gbase + 8 * (WW / 4)];
        float4 p2 = g2 ? img4[gbase + 16 * (WW / 4)] : make_float4(0.f, 0.f, 0.f, 0.f);
        float4* b0 = (float4*)buf[0];
        b0[lw0] = p0;
        b0[lw0 + 8 * LDW4] = p1;
        if (w2) b0[lw0 + 16 * LDW4] = p2;
    }
    __syncthreads();

    const float* __restrict__ kb = ker + (n * CCH) * 9;   // block-uniform -> s_loads

    for (int c = 0; c < CCH; ++c) {
        // prefetch channel c+1 into registers (latency hides under compute)
        float4 p0, p1, p2;
        const bool more = (c + 1 < CCH);
        if (more) {
            int gb = gbase + (c + 1) * (HH * WW / 4);
            p0 = img4[gb];
            p1 = img4[gb + 8 * (WW / 4)];
            p2 = g2 ? img4[gb + 16 * (WW / 4)] : make_float4(0.f, 0.f, 0.f, 0.f);
        }

        // weights for channel c (uniform -> scalar loads)
        float w[9];
        #pragma unroll
        for (int q = 0; q < 9; ++q) w[q] = kb[c * 9 + q];

        // LDS -> registers: 4 rows x 8 floats
        const float* bc = buf[c & 1];
        float f[4][8];
        #pragma unroll
        for (int r = 0; r < 4; ++r) {
            float4 a  = *(const float4*)&bc[(r0 + r) * LDW + c0];
            float4 b2 = *(const float4*)&bc[(r0 + r) * LDW + c0 + 4];
            f[r][0] = a.x;  f[r][1] = a.y;  f[r][2] = a.z;  f[r][3] = a.w;
            f[r][4] = b2.x; f[r][5] = b2.y; f[r][6] = b2.z; f[r][7] = b2.w;
        }

        // 72 FMAs
        #pragma unroll
        for (int kh = 0; kh < 3; ++kh) {
            #pragma unroll
            for (int kw = 0; kw < 3; ++kw) {
                const float wv = w[kh * 3 + kw];
                #pragma unroll
                for (int j = 0; j < 4; ++j) {
                    acc0[j] = fmaf(wv, f[kh][j + kw], acc0[j]);
                    acc1[j] = fmaf(wv, f[kh + 1][j + kw], acc1[j]);
                }
            }
        }

        if (more) {
            float4* bn = (float4*)buf[(c + 1) & 1];
            bn[lw0] = p0;
            bn[lw0 + 8 * LDW4] = p1;
            if (w2) bn[lw0 + 16 * LDW4] = p2;
            __syncthreads();
        }
    }

    // ---- store 2x4 outputs, guard edges (oh<126, ow<126) ----
    const int oh0 = h0 + r0;
    #pragma unroll
    for (int orow = 0; orow < 2; ++orow) {
        const int oh = oh0 + orow;
        if (oh < OHH) {
            float* op = out + (n * OHH + oh) * OWW + c0;
            const float* a = orow ? acc1 : acc0;
            #pragma unroll
            for (int j = 0; j < 4; ++j)
                if (c0 + j < OWW) op[j] = a[j];
        }
    }
}

extern "C" void kernel_launch(void* const* d_in, const int* in_sizes, int n_in,
                              void* d_out, int out_size, void* d_ws, size_t ws_size,
                              hipStream_t stream) {
    const float* img = (const float*)d_in[0];   // [64,64,128,128] f32
    const float* ker = (const float*)d_in[1];   // [64,64,3,3] f32
    float* out = (float*)d_out;                 // [64,1,126,126] f32

    dim3 grid(NS * 8);   // 512 blocks: 64 samples x 8 row-tiles
    dim3 block(256);
    ImageWiseConv2d_kernel<<<grid, block, 0, stream>>>(img, ker, out);
}